// Round 20
// baseline (240.487 us; speedup 1.0000x reference)
//
#include <hip/hip_runtime.h>
#include <math.h>

constexpr int D = 64;
constexpr int H = 4;

// ---------------------------------------------------------------------------
// R19: 238us.  scatter now top (52us): 16x write amplification (53MB for
// 3.2MB) from random 4B stores partial-dirtying lines across 8 XCDs' L2s.
// R20: (1) scatter sc-store -> __builtin_nontemporal_store (bypass L2, LLC
// byte-mask write, no cross-XCD dirty-line merge); (2) aggregate 4 edges per
// wave: lane = dim-QUAD (uint4 = 4k+4v), head reduction = 2 shfl, ~5 inst
// per edge (was 12.5).  KVQ repack free in qkv (lane holds 4 adjacent dims).
// Layouts (verified learn_hip m89/m120): A[m=lane&15][k=(lane>>4)*8+j],
// B[k][n=lane&15] with permuted col map 4m+ct, C/D col=lane&15 row=quad*4+reg.
// ---------------------------------------------------------------------------

typedef __attribute__((ext_vector_type(8))) short bf16x8;
typedef __attribute__((ext_vector_type(4))) float f32x4;

__device__ __forceinline__ unsigned short f32_to_bf16(float f) {
    const unsigned int u = __float_as_uint(f);
    return (unsigned short)((u + 0x7FFFu + ((u >> 16) & 1u)) >> 16);  // RNE
}
__device__ __forceinline__ float bf16_to_f32(unsigned short h) {
    return __uint_as_float(((unsigned int)h) << 16);
}
__device__ __forceinline__ float bf16lo_f32(unsigned int w) {   // bits 0-15
    return __uint_as_float(w << 16);
}
__device__ __forceinline__ float bf16hi_f32(unsigned int w) {   // bits 16-31
    return __uint_as_float(w & 0xFFFF0000u);
}
__device__ __forceinline__ unsigned int pack2(float a, float b) {
    return (unsigned int)f32_to_bf16(a) | ((unsigned int)f32_to_bf16(b) << 16);
}

// ---------------------------------------------------------------------------
// Kernel 0: pre-split W into hi/lo MFMA B-fragment order, permuted col map:
// fragment (mt, ct, ks, lane l, j) <- W_mt[ks*32+(l>>4)*8+j][4*(l&15)+ct]
// so MFMA acc[mt][ct] at lane m holds ORIGINAL output col 4m+ct.
// ---------------------------------------------------------------------------
__global__ __launch_bounds__(256) void prep_w_kernel(
    const float* __restrict__ Wq, const float* __restrict__ Wk,
    const float* __restrict__ Wv,
    unsigned short* __restrict__ WfH, unsigned short* __restrict__ WfL) {
    const float* W[3] = {Wq, Wk, Wv};
    for (int idx = threadIdx.x; idx < 3 * 4 * 2 * 64 * 8; idx += 256) {
        const int j  = idx & 7;
        const int l  = (idx >> 3) & 63;
        const int ks = (idx >> 9) & 1;
        const int ct = (idx >> 10) & 3;
        const int mt = idx >> 12;
        const int krow = ks * 32 + (l >> 4) * 8 + j;
        const int col  = 4 * (l & 15) + ct;          // permuted column map
        const float w  = W[mt][krow * 64 + col];
        const unsigned short h = f32_to_bf16(w);
        WfH[idx] = h;
        WfL[idx] = f32_to_bf16(w - bf16_to_f32(h));
    }
}

// ---------------------------------------------------------------------------
// Kernel 1: QKV projection via split-precision MFMA (Ah*Bh + Ah*Bl + Al*Bh).
// Block = 4 waves; wave = 16 nodes.  Wf hi/lo staged in LDS (48 KB).
// Outputs: Q fp32 (dwordx4/lane), KVQ uint4 = {k01,k23,v01,v23} per dim-quad.
// ---------------------------------------------------------------------------
__global__ __launch_bounds__(256) void qkv_kernel(
    const float* __restrict__ emb,
    const unsigned short* __restrict__ WfH,
    const unsigned short* __restrict__ WfL,
    int N, float* __restrict__ Q, uint4* __restrict__ KVQ) {
    __shared__ unsigned short sH[12288];   // 24 KB
    __shared__ unsigned short sL[12288];   // 24 KB
    const int tid = threadIdx.x;

    {
        const uint4* gh = (const uint4*)WfH;
        const uint4* gl = (const uint4*)WfL;
        uint4* shh = (uint4*)sH;
        uint4* sll = (uint4*)sL;
        for (int k = tid; k < 1536; k += 256) {
            shh[k] = gh[k];
            sll[k] = gl[k];
        }
    }
    __syncthreads();

    const int wv = tid >> 6;
    const int l  = tid & 63;
    const int qd = l >> 4;              // quad 0..3
    const int m  = l & 15;
    const int n0 = blockIdx.x * 64 + wv * 16;

    // A fragments, split hi/lo: k = ks*32 + qd*8 + j
    bf16x8 aH[2], aL[2];
    {
        int node = n0 + m;
        if (node >= N) node = N - 1;
        const float4* ep = (const float4*)(emb + (size_t)node * 64);
#pragma unroll
        for (int ks = 0; ks < 2; ++ks) {
            const float4 a0 = ep[ks * 8 + qd * 2 + 0];
            const float4 a1 = ep[ks * 8 + qd * 2 + 1];
            const float f[8] = {a0.x, a0.y, a0.z, a0.w, a1.x, a1.y, a1.z, a1.w};
            bf16x8 fh, fl;
#pragma unroll
            for (int j = 0; j < 8; ++j) {
                const unsigned short h = f32_to_bf16(f[j]);
                fh[j] = (short)h;
                fl[j] = (short)f32_to_bf16(f[j] - bf16_to_f32(h));
            }
            aH[ks] = fh;
            aL[ks] = fl;
        }
    }

    f32x4 acc[3][4];
#pragma unroll
    for (int mt = 0; mt < 3; ++mt)
#pragma unroll
        for (int ct = 0; ct < 4; ++ct) acc[mt][ct] = (f32x4){0.f, 0.f, 0.f, 0.f};

#pragma unroll
    for (int mt = 0; mt < 3; ++mt) {
#pragma unroll
        for (int ct = 0; ct < 4; ++ct) {
#pragma unroll
            for (int ks = 0; ks < 2; ++ks) {
                const int fi = (((mt * 4 + ct) * 2 + ks) * 64 + l) * 8;
                bf16x8 bh = *(const bf16x8*)&sH[fi];
                bf16x8 bl = *(const bf16x8*)&sL[fi];
                acc[mt][ct] = __builtin_amdgcn_mfma_f32_16x16x32_bf16(
                    aH[ks], bh, acc[mt][ct], 0, 0, 0);
                acc[mt][ct] = __builtin_amdgcn_mfma_f32_16x16x32_bf16(
                    aH[ks], bl, acc[mt][ct], 0, 0, 0);
                acc[mt][ct] = __builtin_amdgcn_mfma_f32_16x16x32_bf16(
                    aL[ks], bh, acc[mt][ct], 0, 0, 0);
            }
        }
    }

    // Epilogue: lane holds original cols 4m+ct (ct=0..3), row = qd*4 + r.
#pragma unroll
    for (int r = 0; r < 4; ++r) {
        const int node = n0 + qd * 4 + r;
        if (node < N) {
            float4 oq;
            oq.x = acc[0][0][r]; oq.y = acc[0][1][r];
            oq.z = acc[0][2][r]; oq.w = acc[0][3][r];
            *(float4*)(Q + (size_t)node * 64 + 4 * m) = oq;

            uint4 kv;   // {k(4m)|k(4m+1), k(4m+2)|k(4m+3), v...}
            kv.x = pack2(acc[1][0][r], acc[1][1][r]);
            kv.y = pack2(acc[1][2][r], acc[1][3][r]);
            kv.z = pack2(acc[2][0][r], acc[2][1][r]);
            kv.w = pack2(acc[2][2][r], acc[2][3][r]);
            KVQ[(size_t)node * 16 + m] = kv;
        }
    }
}

// --- Counting sort: histogram -> block sums -> block scan(+prefix) -> scatter

__global__ __launch_bounds__(256) void histo_kernel(
    const int* __restrict__ rows, int* __restrict__ cnt, int E) {
    const int e = blockIdx.x * 256 + threadIdx.x;
    if (e < E) atomicAdd(&cnt[rows[e]], 1);
}

__global__ __launch_bounds__(256) void block_sum_kernel(
    const int* __restrict__ cnt, int* __restrict__ bsum, int N) {
    __shared__ int s[256];
    const int tid = threadIdx.x;
    const int i   = blockIdx.x * 256 + tid;
    s[tid] = (i < N) ? cnt[i] : 0;
    __syncthreads();
    for (int st = 128; st > 0; st >>= 1) {
        if (tid < st) s[tid] += s[tid + st];
        __syncthreads();
    }
    if (tid == 0) bsum[blockIdx.x] = s[0];
}

__global__ __launch_bounds__(256) void block_scan_kernel(
    const int* __restrict__ cnt, const int* __restrict__ bsum,
    int* __restrict__ off, int* __restrict__ cur, int N, int E, int NB) {
    __shared__ int s[256];
    __shared__ int red[256];
    const int tid = threadIdx.x;
    const int bid = blockIdx.x;
    const int i   = bid * 256 + tid;

    int pacc = 0;
    for (int k = tid; k < NB; k += 256) {
        if (k < bid) pacc += bsum[k];
    }
    red[tid] = pacc;
    __syncthreads();
    for (int st = 128; st > 0; st >>= 1) {
        if (tid < st) red[tid] += red[tid + st];
        __syncthreads();
    }
    const int base = red[0];

    const int x = (i < N) ? cnt[i] : 0;
    s[tid] = x;
    __syncthreads();
    for (int offs = 1; offs < 256; offs <<= 1) {
        int v = 0;
        if (tid >= offs) v = s[tid - offs];
        __syncthreads();
        if (tid >= offs) s[tid] += v;
        __syncthreads();
    }
    if (i < N) {
        const int val = base + s[tid] - x;   // exclusive
        off[i] = val;
        cur[i] = val;
    }
    if (i == 0) off[N] = E;
}

__global__ __launch_bounds__(256) void scatter_kernel(
    const int* __restrict__ rows, const int* __restrict__ cols,
    int* __restrict__ cur, int* __restrict__ sc, int E) {
    const int e = blockIdx.x * 256 + threadIdx.x;
    if (e >= E) return;
    const int p = atomicAdd(&cur[rows[e]], 1);
    __builtin_nontemporal_store(cols[e], &sc[p]);   // bypass L2: no partial-
                                                    // line cross-XCD merges
}

// ---------------------------------------------------------------------------
// Kernel 2: atomic-free aggregation, 4 edges per wave.
// lane l: q = l&15 (dim quad 4q..4q+3), ep = l>>4 (edge slot 0..3).
// Per step: 4 edges in parallel; head dot = 2 shfl (4-lane group); final
// cross-slot combine via shfl_xor(16)+(32).  Main loop 8 edges (2 gathers
// in flight); masked 4-edge tail.
// ---------------------------------------------------------------------------
__global__ __launch_bounds__(256) void aggregate_kernel(
    const int* __restrict__ off, const int* __restrict__ sc,
    const float* __restrict__ Q, const uint4* __restrict__ KVQ,
    float* __restrict__ out, int N) {
    const int t = blockIdx.x * 256 + threadIdx.x;
    const int n = t >> 6;
    const int l = t & 63;
    if (n >= N) return;
    const int q  = l & 15;
    const int ep = l >> 4;

    const int off0 = off[n];
    const int off1 = off[n + 1];
    const float4 q4 = *(const float4*)(Q + (size_t)n * 64 + 4 * q);

    float4 accV = make_float4(0.f, 0.f, 0.f, 0.f);
    float accN = 0.f;
    int i = off0;

    // Main: 8 edges per iteration (2 slot-steps, 2 gathers in flight).
    for (; i + 7 < off1; i += 8) {
        const int c0 = sc[i + ep];
        const int c1 = sc[i + 4 + ep];
        const uint4 kv0 = KVQ[(size_t)c0 * 16 + q];
        const uint4 kv1 = KVQ[(size_t)c1 * 16 + q];
        {
            float pp = q4.x * bf16lo_f32(kv0.x);
            pp = fmaf(q4.y, bf16hi_f32(kv0.x), pp);
            pp = fmaf(q4.z, bf16lo_f32(kv0.y), pp);
            pp = fmaf(q4.w, bf16hi_f32(kv0.y), pp);
            pp += __shfl_xor(pp, 1);
            pp += __shfl_xor(pp, 2);
            const float e = __expf(fminf(fmaxf(pp, -10.f), 10.f));
            accN += e;
            accV.x = fmaf(e, bf16lo_f32(kv0.z), accV.x);
            accV.y = fmaf(e, bf16hi_f32(kv0.z), accV.y);
            accV.z = fmaf(e, bf16lo_f32(kv0.w), accV.z);
            accV.w = fmaf(e, bf16hi_f32(kv0.w), accV.w);
        }
        {
            float pp = q4.x * bf16lo_f32(kv1.x);
            pp = fmaf(q4.y, bf16hi_f32(kv1.x), pp);
            pp = fmaf(q4.z, bf16lo_f32(kv1.y), pp);
            pp = fmaf(q4.w, bf16hi_f32(kv1.y), pp);
            pp += __shfl_xor(pp, 1);
            pp += __shfl_xor(pp, 2);
            const float e = __expf(fminf(fmaxf(pp, -10.f), 10.f));
            accN += e;
            accV.x = fmaf(e, bf16lo_f32(kv1.z), accV.x);
            accV.y = fmaf(e, bf16hi_f32(kv1.z), accV.y);
            accV.z = fmaf(e, bf16lo_f32(kv1.w), accV.z);
            accV.w = fmaf(e, bf16hi_f32(kv1.w), accV.w);
        }
    }
    // Tail: 4 edges per step with validity masking.
    for (; i < off1; i += 4) {
        const int idx = i + ep;
        const bool ok = idx < off1;
        const int c   = sc[ok ? idx : off1 - 1];
        const uint4 kv = KVQ[(size_t)c * 16 + q];
        float pp = q4.x * bf16lo_f32(kv.x);
        pp = fmaf(q4.y, bf16hi_f32(kv.x), pp);
        pp = fmaf(q4.z, bf16lo_f32(kv.y), pp);
        pp = fmaf(q4.w, bf16hi_f32(kv.y), pp);
        pp += __shfl_xor(pp, 1);
        pp += __shfl_xor(pp, 2);
        float e = __expf(fminf(fmaxf(pp, -10.f), 10.f));
        e = ok ? e : 0.f;
        accN += e;
        accV.x = fmaf(e, bf16lo_f32(kv.z), accV.x);
        accV.y = fmaf(e, bf16hi_f32(kv.z), accV.y);
        accV.z = fmaf(e, bf16lo_f32(kv.w), accV.z);
        accV.w = fmaf(e, bf16hi_f32(kv.w), accV.w);
    }

    // Combine the four edge slots.
    accN   += __shfl_xor(accN, 16);   accN   += __shfl_xor(accN, 32);
    accV.x += __shfl_xor(accV.x, 16); accV.x += __shfl_xor(accV.x, 32);
    accV.y += __shfl_xor(accV.y, 16); accV.y += __shfl_xor(accV.y, 32);
    accV.z += __shfl_xor(accV.z, 16); accV.z += __shfl_xor(accV.z, 32);
    accV.w += __shfl_xor(accV.w, 16); accV.w += __shfl_xor(accV.w, 32);

    if (l < 16) {
        const float inv = 1.f / (accN + 1e-8f);
        float4 o;
        o.x = accV.x * inv; o.y = accV.y * inv;
        o.z = accV.z * inv; o.w = accV.w * inv;
        *(float4*)(out + (size_t)n * 64 + 4 * q) = o;
    }
}

extern "C" void kernel_launch(void* const* d_in, const int* in_sizes, int n_in,
                              void* d_out, int out_size, void* d_ws, size_t ws_size,
                              hipStream_t stream) {
    const float* emb = (const float*)d_in[0];
    const float* Wq  = (const float*)d_in[1];
    const float* Wk  = (const float*)d_in[2];
    const float* Wv  = (const float*)d_in[3];
    const int*   w32 = (const int*)d_in[4];

    const int N  = in_sizes[0] / D;   // 100000
    const int E  = in_sizes[4] / 2;   // 800000
    const int NB = (N + 255) / 256;   // 391
    const size_t ND = (size_t)N * D;

    const int* rows = w32;            // validated r10: [2,E], rows = half 0
    const int* cols = w32 + E;

    // Workspace (~59 MB): Q f32 | KVQ uint4 | cnt | off | cur | bsum | sc |
    // WfH | WfL
    float*  ws  = (float*)d_ws;
    float*  Q   = ws;
    uint4*  KVQ = (uint4*)(ws + ND);                       // ND/4 uint4
    int*   cnt  = (int*)(ws + 2 * ND);
    int*   off  = cnt + N;            // N+1
    int*   cur  = off + N + 1;
    int*   bsum = cur + N;
    int*   sc   = bsum + NB + (NB & 1);
    unsigned short* WfH = (unsigned short*)(sc + E);       // 24 KB
    unsigned short* WfL = WfH + 12288;                     // 24 KB

    float* out = (float*)d_out;

    (void)hipMemsetAsync(cnt, 0, (size_t)N * sizeof(int), stream);

    // 0) W -> hi/lo MFMA fragment order (48 KB, single block)
    prep_w_kernel<<<1, 256, 0, stream>>>(Wq, Wk, Wv, WfH, WfL);

    // 1) QKV projection (split-precision MFMA, Wf in LDS, quad outputs)
    qkv_kernel<<<(N + 63) / 64, 256, 0, stream>>>(emb, WfH, WfL, N, Q, KVQ);

    // 2) Counting sort of edges by destination
    histo_kernel<<<(E + 255) / 256, 256, 0, stream>>>(rows, cnt, E);
    block_sum_kernel<<<NB, 256, 0, stream>>>(cnt, bsum, N);
    block_scan_kernel<<<NB, 256, 0, stream>>>(cnt, bsum, off, cur, N, E, NB);
    scatter_kernel<<<(E + 255) / 256, 256, 0, stream>>>(rows, cols, cur, sc, E);

    // 3) Atomic-free aggregation: one wave per node, 4 edges per wave-step
    aggregate_kernel<<<((size_t)N * 64 + 255) / 256, 256, 0, stream>>>(
        off, sc, Q, KVQ, out, N);
}